// Round 3
// baseline (95242.285 us; speedup 1.0000x reference)
//
#include <hip/hip_runtime.h>
#include <math.h>

// ---------------------------------------------------------------------------
// PointerNet rollout on MI355X. fp32 throughout (argmax-exactness required).
// Scratch lives in __device__ globals (.bss) — independent of ws_size, which
// round 1 showed we cannot assume is ~400MB (core dump = OOB page fault).
// PRNG: JAX threefry2x32, partitionable scheme (jax>=0.4.36 default).
// ---------------------------------------------------------------------------

#define JAX_PARTITIONABLE 1

#define Bz 256
#define Sz 256
#define Ez 128
#define Hz 512
#define NEGV -1e9f
#define BH (Bz*Hz)

// ---- device-global scratch (~405 MB, zero-init .bss, allocated at load) ----
__device__ float g_encout[Bz*Sz*Hz];
__device__ float g_glref[Bz*Sz*Hz];
__device__ float g_ptref[Bz*Sz*Hz];
__device__ float g_h[2*BH];
__device__ float g_c[BH];
__device__ float g_q2[BH];
__device__ float g_qg[BH];
__device__ float g_qpt[BH];
__device__ int g_ptrbuf[Bz];
__device__ unsigned g_keys[2*Sz];
__device__ unsigned char g_mask[Bz*Sz];

__device__ __forceinline__ float* buf_by_id(int id){
  switch(id){
    case 0: return g_encout;
    case 1: return g_glref;
    case 2: return g_ptref;
    case 3: return g_h;
    case 4: return g_h + BH;
    case 5: return g_q2;
    case 6: return g_qg;
    default: return g_qpt;  // 7
  }
}

__device__ __forceinline__ unsigned rotl32(unsigned v, int d){ return (v<<d)|(v>>(32-d)); }

__device__ __forceinline__ void tf2x32(unsigned k0, unsigned k1, unsigned x0, unsigned x1,
                                       unsigned &o0, unsigned &o1){
  unsigned ks2 = k0 ^ k1 ^ 0x1BD11BDAu;
  x0 += k0; x1 += k1;
#define TFR(r) { x0 += x1; x1 = rotl32(x1,(r)); x1 ^= x0; }
  TFR(13) TFR(15) TFR(26) TFR(6)
  x0 += k1; x1 += ks2 + 1u;
  TFR(17) TFR(29) TFR(16) TFR(24)
  x0 += ks2; x1 += k0 + 2u;
  TFR(13) TFR(15) TFR(26) TFR(6)
  x0 += k0; x1 += k1 + 3u;
  TFR(17) TFR(29) TFR(16) TFR(24)
  x0 += k1; x1 += ks2 + 4u;
  TFR(13) TFR(15) TFR(26) TFR(6)
  x0 += ks2; x1 += k0 + 5u;
#undef TFR
  o0 = x0; o1 = x1;
}

// 32-bit random draw for flat element idx under step key (ka,kb)
__device__ __forceinline__ unsigned rng_bits(unsigned ka, unsigned kb, unsigned idx){
#if JAX_PARTITIONABLE
  unsigned o0,o1; tf2x32(ka,kb, 0u, idx, o0,o1);
  return o0 ^ o1;
#else
  unsigned o0,o1;
  if (idx < 32768u){ tf2x32(ka,kb, idx, idx+32768u, o0,o1); return o0; }
  else            { tf2x32(ka,kb, idx-32768u, idx, o0,o1); return o1; }
#endif
}

// ---------------------------------------------------------------------------
// init: zero h0, c, mask; generate the 256 per-step keys from key(1)=(0,1)
// ---------------------------------------------------------------------------
__global__ __launch_bounds__(256) void init_kernel(){
  int i = blockIdx.x*256 + threadIdx.x;
  if (i < BH){ g_h[i] = 0.f; g_c[i] = 0.f; }
  if (i < Bz*Sz) g_mask[i] = 0;
  if (i < Sz){
#if JAX_PARTITIONABLE
    unsigned o0,o1; tf2x32(0u,1u, 0u, (unsigned)i, o0,o1);
    g_keys[2*i] = o0; g_keys[2*i+1] = o1;
#else
    // legacy split: key_t = (out[2t], out[2t+1]) of threefry(key, iota(512))
    unsigned a0,a1,b0,b1;
    tf2x32(0u,1u, (unsigned)(2*i),   (unsigned)(2*i+Sz),   a0,a1);
    tf2x32(0u,1u, (unsigned)(2*i+1), (unsigned)(2*i+1+Sz), b0,b1);
    g_keys[2*i] = a0; g_keys[2*i+1] = b0;
#endif
  }
}

// ---------------------------------------------------------------------------
// Fused LSTM step: gates = x@Wih^T + h@Whh^T + b ; pointwise; write h (and
// enc_out for encoder). Tile: 32 b x 16 j x 4 gates per WG. grid (8,32), 256 thr.
// hsel: h_in = g_h + hsel*BH, h_out = the other buffer.
// ---------------------------------------------------------------------------
__global__ __launch_bounds__(256) void lstm_step(
    const float* __restrict__ Wih,   // [2048][128]
    const float* __restrict__ Whh,   // [2048][512]
    const float* __restrict__ bias,  // [2048]
    const float* __restrict__ emb_table, // [Sz][Ez]
    const int*   __restrict__ inputs,    // [Bz][Sz]
    const float* __restrict__ dec_start, // [Ez] (decoder t==0)
    int t, int is_dec, int hsel)
{
  __shared__ float A_lds[32][34];  // [k][b]
  __shared__ float W_lds[32][66];  // [k][r], r = gate*16 + jj

  const float* h_in = g_h + (size_t)hsel*BH;
  float*       h_out = g_h + (size_t)(hsel^1)*BH;

  int tid = threadIdx.x;
  int btile = blockIdx.x;          // 0..7
  int jtile = blockIdx.y;          // 0..31
  int jj = tid & 15;
  int bp = tid >> 4;               // 0..15
  int jglob = jtile*16 + jj;

  float acc[2][4];
  {
    float b0v = bias[0*Hz + jglob];
    float b1v = bias[1*Hz + jglob];
    float b2v = bias[2*Hz + jglob];
    float b3v = bias[3*Hz + jglob];
    acc[0][0]=b0v; acc[0][1]=b1v; acc[0][2]=b2v; acc[0][3]=b3v;
    acc[1][0]=b0v; acc[1][1]=b1v; acc[1][2]=b2v; acc[1][3]=b3v;
  }

  int lb  = tid >> 3;          // 0..31  A-stage row (b)
  int lk4 = (tid & 7) * 4;     // A-stage k offset (float4)
  int lr  = tid >> 2;          // 0..63  W-stage row
  int lk8 = (tid & 3) * 8;     // W-stage k offset (8 floats)
  int wR  = (lr >> 4)*Hz + jtile*16 + (lr & 15);  // global weight row

  for (int kc = 0; kc < 20; kc++){
    int k0 = kc*32;
    __syncthreads();
    // stage A
    {
      int bglob = btile*32 + lb;
      float4 av;
      if (k0 < Ez){
        const float* xrow;
        if (is_dec){
          if (t == 0) xrow = dec_start;
          else        xrow = emb_table + (size_t)inputs[bglob*Sz + g_ptrbuf[bglob]] * Ez;
        } else {
          xrow = emb_table + (size_t)inputs[bglob*Sz + t] * Ez;
        }
        av = *(const float4*)(xrow + k0 + lk4);
      } else {
        av = *(const float4*)(h_in + (size_t)bglob*Hz + (k0 - Ez) + lk4);
      }
      A_lds[lk4+0][lb] = av.x; A_lds[lk4+1][lb] = av.y;
      A_lds[lk4+2][lb] = av.z; A_lds[lk4+3][lb] = av.w;
    }
    // stage W
    {
      const float* wrow = (k0 < Ez) ? (Wih + (size_t)wR*Ez + k0)
                                    : (Whh + (size_t)wR*Hz + (k0 - Ez));
      float4 w0 = *(const float4*)(wrow + lk8);
      float4 w1 = *(const float4*)(wrow + lk8 + 4);
      W_lds[lk8+0][lr]=w0.x; W_lds[lk8+1][lr]=w0.y; W_lds[lk8+2][lr]=w0.z; W_lds[lk8+3][lr]=w0.w;
      W_lds[lk8+4][lr]=w1.x; W_lds[lk8+5][lr]=w1.y; W_lds[lk8+6][lr]=w1.z; W_lds[lk8+7][lr]=w1.w;
    }
    __syncthreads();
    #pragma unroll
    for (int k=0;k<32;k++){
      float2 a = *(const float2*)&A_lds[k][bp*2];
      float w0 = W_lds[k][jj];
      float w1 = W_lds[k][16+jj];
      float w2 = W_lds[k][32+jj];
      float w3 = W_lds[k][48+jj];
      acc[0][0] = fmaf(a.x, w0, acc[0][0]);
      acc[0][1] = fmaf(a.x, w1, acc[0][1]);
      acc[0][2] = fmaf(a.x, w2, acc[0][2]);
      acc[0][3] = fmaf(a.x, w3, acc[0][3]);
      acc[1][0] = fmaf(a.y, w0, acc[1][0]);
      acc[1][1] = fmaf(a.y, w1, acc[1][1]);
      acc[1][2] = fmaf(a.y, w2, acc[1][2]);
      acc[1][3] = fmaf(a.y, w3, acc[1][3]);
    }
  }

  int b0 = btile*32 + bp*2;
  #pragma unroll
  for (int r=0;r<2;r++){
    int b = b0 + r;
    float gi = acc[r][0], gf = acc[r][1], gg = acc[r][2], go = acc[r][3];
    float co = g_c[(size_t)b*Hz + jglob];
    float si = 1.f/(1.f + expf(-gi));
    float sf = 1.f/(1.f + expf(-gf));
    float so = 1.f/(1.f + expf(-go));
    float cn = sf*co + si*tanhf(gg);
    float hn = so*tanhf(cn);
    g_c[(size_t)b*Hz + jglob] = cn;
    h_out[(size_t)b*Hz + jglob] = hn;
    if (!is_dec) g_encout[((size_t)b*Sz + t)*Hz + jglob] = hn;
  }
}

// ---------------------------------------------------------------------------
// C[M][512] = A[M][512] @ W[512][512]^T + bias. 64x64 tile, thread 4x4, Kt=32.
// A/C are device-global buffers selected by id (see buf_by_id).
// ---------------------------------------------------------------------------
__global__ __launch_bounds__(256) void gemm_qlin(
    const float* __restrict__ W, const float* __restrict__ bias,
    int src_id, int dst_id)
{
  const float* A = buf_by_id(src_id);
  float*       C = buf_by_id(dst_id);
  __shared__ float As[32][68];
  __shared__ float Ws[32][68];
  int tid = threadIdx.x;
  int mt = blockIdx.x * 64, nt = blockIdx.y * 64;
  int tm = (tid & 15) * 4, tn = (tid >> 4) * 4;
  float acc[4][4] = {};
  int lr = tid >> 2;        // 0..63
  int lk = (tid & 3) * 8;

  for (int kc = 0; kc < 16; kc++){
    int k0 = kc*32;
    __syncthreads();
    {
      const float* ar = A + (size_t)(mt + lr)*Hz + k0 + lk;
      float4 a0 = *(const float4*)ar, a1 = *(const float4*)(ar+4);
      As[lk+0][lr]=a0.x; As[lk+1][lr]=a0.y; As[lk+2][lr]=a0.z; As[lk+3][lr]=a0.w;
      As[lk+4][lr]=a1.x; As[lk+5][lr]=a1.y; As[lk+6][lr]=a1.z; As[lk+7][lr]=a1.w;
      const float* wr = W + (size_t)(nt + lr)*Hz + k0 + lk;
      float4 w0 = *(const float4*)wr, w1 = *(const float4*)(wr+4);
      Ws[lk+0][lr]=w0.x; Ws[lk+1][lr]=w0.y; Ws[lk+2][lr]=w0.z; Ws[lk+3][lr]=w0.w;
      Ws[lk+4][lr]=w1.x; Ws[lk+5][lr]=w1.y; Ws[lk+6][lr]=w1.z; Ws[lk+7][lr]=w1.w;
    }
    __syncthreads();
    #pragma unroll
    for (int k=0;k<32;k++){
      float4 av = *(const float4*)&As[k][tm];
      float4 wv = *(const float4*)&Ws[k][tn];
      acc[0][0]=fmaf(av.x,wv.x,acc[0][0]); acc[0][1]=fmaf(av.x,wv.y,acc[0][1]);
      acc[0][2]=fmaf(av.x,wv.z,acc[0][2]); acc[0][3]=fmaf(av.x,wv.w,acc[0][3]);
      acc[1][0]=fmaf(av.y,wv.x,acc[1][0]); acc[1][1]=fmaf(av.y,wv.y,acc[1][1]);
      acc[1][2]=fmaf(av.y,wv.z,acc[1][2]); acc[1][3]=fmaf(av.y,wv.w,acc[1][3]);
      acc[2][0]=fmaf(av.z,wv.x,acc[2][0]); acc[2][1]=fmaf(av.z,wv.y,acc[2][1]);
      acc[2][2]=fmaf(av.z,wv.z,acc[2][2]); acc[2][3]=fmaf(av.z,wv.w,acc[2][3]);
      acc[3][0]=fmaf(av.w,wv.x,acc[3][0]); acc[3][1]=fmaf(av.w,wv.y,acc[3][1]);
      acc[3][2]=fmaf(av.w,wv.z,acc[3][2]); acc[3][3]=fmaf(av.w,wv.w,acc[3][3]);
    }
  }
  float b0v = bias[nt+tn+0], b1v = bias[nt+tn+1], b2v = bias[nt+tn+2], b3v = bias[nt+tn+3];
  #pragma unroll
  for (int i=0;i<4;i++){
    float4 o;
    o.x = acc[i][0] + b0v; o.y = acc[i][1] + b1v;
    o.z = acc[i][2] + b2v; o.w = acc[i][3] + b3v;
    *(float4*)(C + (size_t)(mt + tm + i)*Hz + nt + tn) = o;
  }
}

// ---------------------------------------------------------------------------
// Glimpse: per-b WG. Online-softmax fused attention:
//   logit_s = V . tanh(q2[b] + gl_ref[b,s,:]) (masked -> -1e9)
//   qg[b]   = sum_s softmax(logit)_s * gl_ref[b,s,:]
// ---------------------------------------------------------------------------
__global__ __launch_bounds__(256) void glimpse_kernel(const float* __restrict__ V)
{
  int b = blockIdx.x, tid = threadIdx.x;
  __shared__ float qs[Hz];
  __shared__ float vs[Hz];
  __shared__ float tile[8][Hz];
  __shared__ float lg8[8];

  qs[tid]       = g_q2[(size_t)b*Hz + tid];
  qs[256 + tid] = g_q2[(size_t)b*Hz + 256 + tid];
  vs[tid]       = V[tid];
  vs[256 + tid] = V[256 + tid];

  int g = tid >> 5, lane = tid & 31;
  int h2 = tid * 2;
  float m = -INFINITY, l = 0.f, acc0 = 0.f, acc1 = 0.f;
  __syncthreads();

  for (int c = 0; c < 32; c++){
    int s0 = c*8;
    {
      int srow = s0 + g;
      float4* dst = (float4*)&tile[g][lane*16];
      if (g_mask[b*Sz + srow]){
        float4 z = {0.f,0.f,0.f,0.f};
        dst[0]=z; dst[1]=z; dst[2]=z; dst[3]=z;
      } else {
        const float4* src = (const float4*)(g_glref + ((size_t)b*Sz + srow)*Hz + lane*16);
        dst[0]=src[0]; dst[1]=src[1]; dst[2]=src[2]; dst[3]=src[3];
      }
    }
    __syncthreads();
    {
      int srow = s0 + g;
      float lgv;
      if (g_mask[b*Sz + srow]) lgv = NEGV;
      else {
        float p = 0.f;
        #pragma unroll
        for (int mm=0;mm<16;mm++){
          int hh = lane + mm*32;
          p = fmaf(vs[hh], tanhf(qs[hh] + tile[g][hh]), p);
        }
        #pragma unroll
        for (int off=16; off; off>>=1) p += __shfl_xor(p, off, 32);
        lgv = p;
      }
      if (lane == 0) lg8[g] = lgv;
    }
    __syncthreads();
    {
      float l0=lg8[0],l1=lg8[1],l2=lg8[2],l3=lg8[3],l4=lg8[4],l5=lg8[5],l6=lg8[6],l7=lg8[7];
      float mx = fmaxf(fmaxf(fmaxf(l0,l1),fmaxf(l2,l3)), fmaxf(fmaxf(l4,l5),fmaxf(l6,l7)));
      float m_new = fmaxf(m, mx);
      float r_ = expf(m - m_new);       // m=-inf -> 0
      float p0=expf(l0-m_new), p1=expf(l1-m_new), p2=expf(l2-m_new), p3=expf(l3-m_new);
      float p4=expf(l4-m_new), p5=expf(l5-m_new), p6=expf(l6-m_new), p7=expf(l7-m_new);
      float ps = ((p0+p1)+(p2+p3)) + ((p4+p5)+(p6+p7));
      float a0 = p0*tile[0][h2] + p1*tile[1][h2] + p2*tile[2][h2] + p3*tile[3][h2]
               + p4*tile[4][h2] + p5*tile[5][h2] + p6*tile[6][h2] + p7*tile[7][h2];
      float a1 = p0*tile[0][h2+1] + p1*tile[1][h2+1] + p2*tile[2][h2+1] + p3*tile[3][h2+1]
               + p4*tile[4][h2+1] + p5*tile[5][h2+1] + p6*tile[6][h2+1] + p7*tile[7][h2+1];
      acc0 = acc0*r_ + a0;
      acc1 = acc1*r_ + a1;
      l    = l*r_ + ps;
      m = m_new;
    }
    __syncthreads();
  }
  g_qg[(size_t)b*Hz + h2]     = acc0 / l;
  g_qg[(size_t)b*Hz + h2 + 1] = acc1 / l;
}

// ---------------------------------------------------------------------------
// Pointer logits + Gumbel-max sample + log_softmax + mask update. Per-b WG.
// ---------------------------------------------------------------------------
__global__ __launch_bounds__(256) void ptr_sample_kernel(
    const float* __restrict__ V, int t, float* __restrict__ out)
{
  int b = blockIdx.x, tid = threadIdx.x;
  __shared__ float qs[Hz];
  __shared__ float vs[Hz];
  __shared__ float slog[Sz];
  __shared__ float wy[4]; __shared__ int wi[4]; __shared__ float wm[4]; __shared__ float wsum[4];

  qs[tid]       = g_qpt[(size_t)b*Hz + tid];
  qs[256 + tid] = g_qpt[(size_t)b*Hz + 256 + tid];
  vs[tid]       = V[tid];
  vs[256 + tid] = V[256 + tid];
  __syncthreads();

  int g = tid >> 5, lane = tid & 31;
  for (int c = 0; c < 32; c++){
    int s = c*8 + g;
    float lgv;
    if (g_mask[b*Sz + s]) lgv = NEGV;
    else {
      const float* row = g_ptref + ((size_t)b*Sz + s)*Hz;
      float p = 0.f;
      #pragma unroll
      for (int mm=0;mm<16;mm++){
        int hh = lane + mm*32;
        p = fmaf(vs[hh], tanhf(qs[hh] + row[hh]), p);
      }
      #pragma unroll
      for (int off=16; off; off>>=1) p += __shfl_xor(p, off, 32);
      lgv = 10.f * tanhf(p);   // CEXP * tanh
    }
    if (lane == 0) slog[s] = lgv;
  }
  __syncthreads();

  // phase B: thread tid owns s = tid
  float lg = slog[tid];
  unsigned bits = rng_bits(g_keys[2*t], g_keys[2*t+1], (unsigned)(b*Sz + tid));
  float u = __uint_as_float((bits >> 9) | 0x3f800000u) - 1.f;
  float gum = -logf(-logf(u + 1e-10f) + 1e-10f);
  float y = lg + gum;

  // argmax(y) with first-index tie-break + max(lg), wave64 butterfly
  float by = y; int bi = tid; float bm = lg;
  #pragma unroll
  for (int off=32; off; off>>=1){
    float oy = __shfl_xor(by, off);
    int   oi = __shfl_xor(bi, off);
    float om = __shfl_xor(bm, off);
    if (oy > by || (oy == by && oi < bi)){ by = oy; bi = oi; }
    bm = fmaxf(bm, om);
  }
  int wid = tid >> 6;
  if ((tid & 63) == 0){ wy[wid]=by; wi[wid]=bi; wm[wid]=bm; }
  __syncthreads();
  float fy = wy[0]; int fi = wi[0]; float fm = wm[0];
  #pragma unroll
  for (int w=1; w<4; w++){
    if (wy[w] > fy || (wy[w] == fy && wi[w] < fi)){ fy = wy[w]; fi = wi[w]; }
    fm = fmaxf(fm, wm[w]);
  }
  int ptr = fi;

  // log-softmax denominator
  float pe = expf(lg - fm);     // masked: exp(-1e9 - fm) = 0
  #pragma unroll
  for (int off=32; off; off>>=1) pe += __shfl_xor(pe, off);
  if ((tid & 63) == 0) wsum[wid] = pe;
  __syncthreads();
  if (tid == 0){
    float den = (wsum[0]+wsum[1]) + (wsum[2]+wsum[3]);
    float logp = slog[ptr] - fm - logf(den);
    out[(size_t)b*Sz + t] = (float)ptr;             // tours
    out[(size_t)Bz*Sz + (size_t)b*Sz + t] = logp;   // logps
    g_mask[b*Sz + ptr] = 1;
    g_ptrbuf[b] = ptr;
  }
}

// ---------------------------------------------------------------------------
extern "C" void kernel_launch(void* const* d_in, const int* in_sizes, int n_in,
                              void* d_out, int out_size, void* d_ws, size_t ws_size,
                              hipStream_t stream){
  (void)in_sizes; (void)n_in; (void)out_size; (void)d_ws; (void)ws_size;
  const float* embedding = (const float*)d_in[0];
  const float* enc_Wih = (const float*)d_in[1];
  const float* enc_Whh = (const float*)d_in[2];
  const float* enc_b   = (const float*)d_in[3];
  const float* dec_Wih = (const float*)d_in[4];
  const float* dec_Whh = (const float*)d_in[5];
  const float* dec_b   = (const float*)d_in[6];
  const float* pt_Wq   = (const float*)d_in[7];
  const float* pt_bq   = (const float*)d_in[8];
  const float* pt_Wref = (const float*)d_in[9];
  const float* pt_bref = (const float*)d_in[10];
  const float* pt_V    = (const float*)d_in[11];
  const float* gl_Wq   = (const float*)d_in[12];
  const float* gl_bq   = (const float*)d_in[13];
  const float* gl_Wref = (const float*)d_in[14];
  const float* gl_bref = (const float*)d_in[15];
  const float* gl_V    = (const float*)d_in[16];
  const float* dec_start = (const float*)d_in[17];
  const int*   inputs  = (const int*)d_in[18];
  float* out = (float*)d_out;

  init_kernel<<<512, 256, 0, stream>>>();

  // ---- encoder ----
  for (int t = 0; t < Sz; t++){
    lstm_step<<<dim3(8,32), 256, 0, stream>>>(enc_Wih, enc_Whh, enc_b,
        embedding, inputs, dec_start, t, 0, t & 1);
  }
  // ---- ref projections (1x1 conv == per-position linear) ----
  gemm_qlin<<<dim3(1024,8), 256, 0, stream>>>(gl_Wref, gl_bref, 0, 1);
  gemm_qlin<<<dim3(1024,8), 256, 0, stream>>>(pt_Wref, pt_bref, 0, 2);

  // ---- decoder ----
  for (int t = 0; t < Sz; t++){
    lstm_step<<<dim3(8,32), 256, 0, stream>>>(dec_Wih, dec_Whh, dec_b,
        embedding, inputs, dec_start, t, 1, t & 1);
    gemm_qlin<<<dim3(4,8), 256, 0, stream>>>(gl_Wq, gl_bq, 3 + ((t+1) & 1), 5);
    glimpse_kernel<<<Bz, 256, 0, stream>>>(gl_V);
    gemm_qlin<<<dim3(4,8), 256, 0, stream>>>(pt_Wq, pt_bq, 6, 7);
    ptr_sample_kernel<<<Bz, 256, 0, stream>>>(pt_V, t, out);
  }
}